// Round 13
// baseline (158.167 us; speedup 1.0000x reference)
//
#include <hip/hip_runtime.h>
#include <hip/hip_bf16.h>

typedef __attribute__((ext_vector_type(4))) float f32x4;
typedef __attribute__((ext_vector_type(16))) float f32x16;
typedef __attribute__((ext_vector_type(8))) short s16x8;
typedef __attribute__((ext_vector_type(4))) unsigned short us16x4;
typedef __attribute__((ext_vector_type(4))) unsigned int u32x4;

#define C_DIM 512
#define S_DIM 4096
#define NB 2
#define NH 8
#define HD 64

// Q prescale: 1/sqrt(64) * log2(e), so attention logits are in exp2 domain
#define QSCALE 0.1803368801111244f

__device__ __forceinline__ unsigned short f2bf(float f) {
    union { float f; unsigned u; } v; v.f = f;
    unsigned r = v.u + 0x7FFFu + ((v.u >> 16) & 1u);
    return (unsigned short)(r >> 16);
}

__device__ __forceinline__ float dev_exp2(float x) {
    float r;
    asm("v_exp_f32 %0, %1" : "=v"(r) : "v"(x));
    return r;
}

__device__ __forceinline__ unsigned cvt_pk_bf16(float lo, float hi) {
    unsigned r;
    asm("v_cvt_pk_bf16_f32 %0, %1, %2" : "=v"(r) : "v"(lo), "v"(hi));
    return r;
}

// v_permlane32_swap_b32 a, b : a[0:31] <-> b[32:63]
__device__ __forceinline__ void lane_swap(unsigned& a, unsigned& b) {
    asm("v_permlane32_swap_b32 %0, %1" : "+v"(a), "+v"(b));
}

// async global -> LDS, 16B per lane; dest = base + lane*16 (base wave-uniform)
__device__ __forceinline__ void gload_lds16(const void* g, void* l) {
    __builtin_amdgcn_global_load_lds(
        (const __attribute__((address_space(1))) void*)g,
        (__attribute__((address_space(3))) void*)l, 16, 0, 0);
}

// ---------------- K0a: weights fp32 -> bf16 ----------------
__global__ __launch_bounds__(256) void wconv_kernel(
    const float* __restrict__ Wq, const float* __restrict__ Wk,
    const float* __restrict__ Wv, const float* __restrict__ Wo,
    unsigned short* __restrict__ Wb) {
    int i = blockIdx.x * 256 + threadIdx.x;          // 0..262143
    int y = blockIdx.y;                               // 0..3
    const float* src = (y == 0) ? Wq : (y == 1) ? Wk : (y == 2) ? Wv : Wo;
    Wb[(size_t)y * 262144 + i] = f2bf(src[i]);
}

// ---------------- K0b: x [N][C][S] f32 -> Xt [N][S][C] bf16 (vectorized, R10-proven) ----
__global__ __launch_bounds__(256) void xpose_kernel(
    const float* __restrict__ x, unsigned short* __restrict__ Xt) {
    __shared__ float tile[32][132];
    int n = blockIdx.z;
    int s0 = blockIdx.x * 128;
    int c0 = blockIdx.y * 32;
    int t = threadIdx.x;
    int cr = t >> 3, scol = (t & 7) * 16;
    const float* src = &x[((size_t)n * C_DIM + c0 + cr) * S_DIM + s0 + scol];
#pragma unroll
    for (int i = 0; i < 4; ++i)
        *(f32x4*)&tile[cr][scol + i * 4] = *(const f32x4*)&src[i * 4];
    __syncthreads();
    int sr = t >> 1, ch = (t & 1) * 16;
    unsigned short* dst = &Xt[((size_t)n * S_DIM + s0 + sr) * C_DIM + c0 + ch];
#pragma unroll
    for (int half = 0; half < 2; ++half) {
        s16x8 pk;
#pragma unroll
        for (int j = 0; j < 8; ++j)
            pk[j] = (short)f2bf(tile[ch + half * 8 + j][sr]);
        *(s16x8*)&dst[half * 8] = pk;
    }
}

// ---------------- K1: QKV projection GEMM (global_load_lds staging) ----------------
__global__ __launch_bounds__(256) void qkv_gemm_kernel(
    const unsigned short* __restrict__ Wb, const unsigned short* __restrict__ Xt,
    const float* __restrict__ bq, const float* __restrict__ bk, const float* __restrict__ bv,
    unsigned short* __restrict__ Qt, unsigned short* __restrict__ Kt,
    unsigned short* __restrict__ Vb) {
    __shared__ unsigned short As[128 * 64];
    __shared__ unsigned short Bs[128 * 64];
    int w = blockIdx.z >> 1;
    int n = blockIdx.z & 1;
    const unsigned short* A = Wb + (size_t)w * 262144;
    const unsigned short* B = Xt + (size_t)n * S_DIM * C_DIM;
    int tid = threadIdx.x;
    int wid = tid >> 6, lane = tid & 63;
    int wm = wid >> 1, wn = wid & 1;
    int lr = lane & 15, lq = lane >> 4;
    int bm = blockIdx.y * 128, bt = blockIdx.x * 128;
    int r_in = lane >> 3, c8 = (lane & 7) * 8;   // staging: 8 rows x 64 cols per issue

    f32x4 zero = {0.f, 0.f, 0.f, 0.f};
    f32x4 acc[4][4];
#pragma unroll
    for (int i = 0; i < 4; ++i)
#pragma unroll
        for (int j = 0; j < 4; ++j) acc[i][j] = zero;

    for (int ks = 0; ks < 8; ++ks) {
#pragma unroll
        for (int q = 0; q < 4; ++q) {
            int row = wid * 32 + q * 8;
            gload_lds16(A + (size_t)(bm + row + r_in) * C_DIM + ks * 64 + c8, &As[row * 64]);
            gload_lds16(B + (size_t)(bt + row + r_in) * C_DIM + ks * 64 + c8, &Bs[row * 64]);
        }
        __syncthreads();
#pragma unroll
        for (int kk = 0; kk < 2; ++kk) {
            s16x8 af[4], bf[4];
#pragma unroll
            for (int i = 0; i < 4; ++i)
                af[i] = *(const s16x8*)&As[(wm * 64 + i * 16 + lr) * 64 + kk * 32 + lq * 8];
#pragma unroll
            for (int j = 0; j < 4; ++j)
                bf[j] = *(const s16x8*)&Bs[(wn * 64 + j * 16 + lr) * 64 + kk * 32 + lq * 8];
#pragma unroll
            for (int i = 0; i < 4; ++i)
#pragma unroll
                for (int j = 0; j < 4; ++j)
                    acc[i][j] = __builtin_amdgcn_mfma_f32_16x16x32_bf16(af[i], bf[j], acc[i][j], 0, 0, 0);
        }
        __syncthreads();
    }

    const float* bias = (w == 0) ? bq : (w == 1) ? bk : bv;
#pragma unroll
    for (int i = 0; i < 4; ++i) {
        int obase = bm + wm * 64 + i * 16 + lq * 4;
#pragma unroll
        for (int j = 0; j < 4; ++j) {
            int t = bt + wn * 64 + j * 16 + lr;
            if (w == 0) {
                us16x4 pk;
#pragma unroll
                for (int r = 0; r < 4; ++r)
                    pk[r] = f2bf((acc[i][j][r] + bias[obase + r]) * QSCALE);
                int h = obase >> 6, d = obase & 63;
                *(us16x4*)&Qt[(((size_t)(n * NH + h) * S_DIM) + t) * HD + d] = pk;
            } else if (w == 1) {
                us16x4 pk;
#pragma unroll
                for (int r = 0; r < 4; ++r) pk[r] = f2bf(acc[i][j][r] + bias[obase + r]);
                int h = obase >> 6, d = obase & 63;
                *(us16x4*)&Kt[(((size_t)(n * NH + h) * S_DIM) + t) * HD + d] = pk;
            } else {
#pragma unroll
                for (int r = 0; r < 4; ++r) {
                    int o = obase + r;
                    Vb[((size_t)(n * C_DIM + o)) * S_DIM + t] = f2bf(acc[i][j][r] + bias[o]);
                }
            }
        }
    }
}

// ---------------- K2: flash attention (R9 compute loop + DMA-staged dbuf K/V) ----------
// Mq=32/wave, NO split, no-max softmax, l-sum via ones-MFMA on matrix pipe.
// K/V staged via global_load_lds DMA into double-buffered LDS: LDS dest is linear
// (DMA writes base+lane*16); the conflict-free swizzle is applied by INVERSE-swizzling
// the per-lane GLOBAL source column (rule: both-sides-or-neither). Read side unchanged
// (phys_slot = slot ^ (row&7) ^ ((row>>3)&3), verified 0 conflicts).
// Removes all ds_writes + staging regs; ONE barrier per tile (its vmcnt drain = DMA fence).
__global__ __launch_bounds__(256) void attn_kernel(
    const unsigned short* __restrict__ Qt, const unsigned short* __restrict__ Kt,
    const unsigned short* __restrict__ Vb, unsigned short* __restrict__ Ot) {
    __shared__ unsigned short Ks[2][64 * 64];   // [buf][kv][d]
    __shared__ unsigned short Vs[2][64 * 64];   // [buf][d][kv]
    int tid = threadIdx.x, wid = tid >> 6, lane = tid & 63;
    int l31 = lane & 31, hi = lane >> 5;
    int radj = (l31 & 7) ^ ((l31 >> 3) & 3);

    // XCD-bijective swizzle: 512 blocks -> 64 consecutive per XCD = 2 heads
    int bidl = blockIdx.x;
    int swz = (bidl & 7) * 64 + (bidl >> 3);
    int nh = swz >> 5;          // 0..15
    int qb = swz & 31;          // 0..31
    int n = nh >> 3, h = nh & 7;
    int qrow0 = qb * 128 + wid * 32;

    const unsigned short* Qh = Qt + (size_t)nh * S_DIM * HD;
    const unsigned short* Kh = Kt + (size_t)nh * S_DIM * HD;
    const unsigned short* Vh = Vb + ((size_t)(n * C_DIM + h * HD)) * S_DIM;

    // Q fragments (B-operand): n=lane&31 -> q, k-dim d = st*16 + hi*8 + j
    s16x8 qf[4];
#pragma unroll
    for (int st = 0; st < 4; ++st)
        qf[st] = *(const s16x8*)&Qh[((size_t)(qrow0 + l31)) * HD + st * 16 + hi * 8];

    // all-ones bf16 A-frag for the l-sum MFMA
    s16x8 ones;
#pragma unroll
    for (int r = 0; r < 8; ++r) ones[r] = (short)0x3F80;

    f32x16 Oacc[2], Lacc;
#pragma unroll
    for (int jm = 0; jm < 2; ++jm)
#pragma unroll
        for (int r = 0; r < 16; ++r) Oacc[jm][r] = 0.f;
#pragma unroll
    for (int r = 0; r < 16; ++r) Lacc[r] = 0.f;

    // DMA staging geometry: each wave stages rows [wid*16, wid*16+16) of K and V.
    // One gload covers 8 rows x 64 cols (64 lanes x 16B). Lane L -> local row L>>3,
    // phys slot L&7; global col inverse-swizzled so reads see the standard layout.
    int lr8 = lane >> 3, pslot = lane & 7;
    int row_a = wid * 16 + lr8;          // rows 0..7 of this wave's chunk
    int row_b = row_a + 8;               // rows 8..15
    int sca = (pslot ^ (row_a & 7) ^ ((row_a >> 3) & 3)) * 8;
    int scb = (pslot ^ (row_b & 7) ^ ((row_b >> 3) & 3)) * 8;
    int rb_a = (wid * 16) * 64;          // wave-uniform LDS element base
    int rb_b = (wid * 16 + 8) * 64;

#define STAGE_KV(buf, kt_) {                                                        \
        const unsigned short* kb_ = Kh + ((size_t)((kt_) * 64)) * HD;               \
        gload_lds16(kb_ + (size_t)row_a * HD + sca, &Ks[buf][rb_a]);                \
        gload_lds16(kb_ + (size_t)row_b * HD + scb, &Ks[buf][rb_b]);                \
        const unsigned short* vb_ = Vh + (kt_) * 64;                                \
        gload_lds16(vb_ + (size_t)row_a * S_DIM + sca, &Vs[buf][rb_a]);             \
        gload_lds16(vb_ + (size_t)row_b * S_DIM + scb, &Vs[buf][rb_b]);             \
    }

    STAGE_KV(0, 0);
    __syncthreads();   // compiler drains vmcnt before barrier -> tile 0 ready

    for (int kt = 0; kt < 64; ++kt) {
        int cur = kt & 1;
        if (kt < 63) STAGE_KV(cur ^ 1, kt + 1);   // DMA fills other buffer during compute

        // ---- QK^T: D[kv][q] per jm tile; A=K rows, B=Q ----
        f32x16 s_[2];
#pragma unroll
        for (int jm = 0; jm < 2; ++jm) {
#pragma unroll
            for (int r = 0; r < 16; ++r) s_[jm][r] = 0.f;
            int arow = jm * 32 + l31;
#pragma unroll
            for (int st = 0; st < 4; ++st) {
                s16x8 kf = *(const s16x8*)&Ks[cur][arow * 64 + ((2 * st + hi) ^ radj) * 8];
                s_[jm] = __builtin_amdgcn_mfma_f32_32x32x16_bf16(kf, qf[st], s_[jm], 0, 0, 0);
            }
        }

        // ---- p = exp2(s) directly (no max pass), pack to PV B-frags in-register ----
        s16x8 pf[2][2];
#pragma unroll
        for (int jm = 0; jm < 2; ++jm) {
            unsigned pk0 = cvt_pk_bf16(dev_exp2(s_[jm][0]),  dev_exp2(s_[jm][1]));
            unsigned pk1 = cvt_pk_bf16(dev_exp2(s_[jm][2]),  dev_exp2(s_[jm][3]));
            unsigned pk2 = cvt_pk_bf16(dev_exp2(s_[jm][4]),  dev_exp2(s_[jm][5]));
            unsigned pk3 = cvt_pk_bf16(dev_exp2(s_[jm][6]),  dev_exp2(s_[jm][7]));
            unsigned pk4 = cvt_pk_bf16(dev_exp2(s_[jm][8]),  dev_exp2(s_[jm][9]));
            unsigned pk5 = cvt_pk_bf16(dev_exp2(s_[jm][10]), dev_exp2(s_[jm][11]));
            unsigned pk6 = cvt_pk_bf16(dev_exp2(s_[jm][12]), dev_exp2(s_[jm][13]));
            unsigned pk7 = cvt_pk_bf16(dev_exp2(s_[jm][14]), dev_exp2(s_[jm][15]));
            lane_swap(pk2, pk0);   // pk2 -> w2, pk0 -> w0 of step 0
            lane_swap(pk3, pk1);   // pk3 -> w3, pk1 -> w1
            lane_swap(pk6, pk4);   // step 1
            lane_swap(pk7, pk5);
            u32x4 w0 = {pk0, pk1, pk2, pk3};
            u32x4 w1 = {pk4, pk5, pk6, pk7};
            pf[jm][0] = __builtin_bit_cast(s16x8, w0);
            pf[jm][1] = __builtin_bit_cast(s16x8, w1);
        }

        // ---- l-sum on the matrix pipe: Lacc[*][q] += sum_kv P[kv][q] ----
#pragma unroll
        for (int jm = 0; jm < 2; ++jm)
#pragma unroll
            for (int st = 0; st < 2; ++st)
                Lacc = __builtin_amdgcn_mfma_f32_32x32x16_bf16(ones, pf[jm][st], Lacc, 0, 0, 0);

        // ---- PV: Oacc[d-tile jm2] += V^T[d][kv] x P[q][kv] ----
#pragma unroll
        for (int jm2 = 0; jm2 < 2; ++jm2) {
            int vrow = jm2 * 32 + l31;
#pragma unroll
            for (int jm = 0; jm < 2; ++jm)
#pragma unroll
                for (int st = 0; st < 2; ++st) {
                    s16x8 vf = *(const s16x8*)&Vs[cur][vrow * 64 + ((jm * 4 + st * 2 + hi) ^ radj) * 8];
                    Oacc[jm2] = __builtin_amdgcn_mfma_f32_32x32x16_bf16(vf, pf[jm][st], Oacc[jm2], 0, 0, 0);
                }
        }

        __syncthreads();   // drains next-tile DMA + releases cur buffer
    }
#undef STAGE_KV

    float inv = 1.f / Lacc[0];
    int token = qrow0 + l31;
    unsigned short* orow = Ot + ((size_t)n * S_DIM + token) * C_DIM + h * HD;
#pragma unroll
    for (int jm2 = 0; jm2 < 2; ++jm2)
#pragma unroll
        for (int rq = 0; rq < 4; ++rq) {
            int d = jm2 * 32 + 8 * rq + 4 * hi;
            us16x4 pk;
#pragma unroll
            for (int r = 0; r < 4; ++r) pk[r] = f2bf(Oacc[jm2][rq * 4 + r] * inv);
            *(us16x4*)&orow[d] = pk;
        }
}

// ---------------- K3: output projection + residual (global_load_lds staging) ----------------
__global__ __launch_bounds__(256) void out_gemm_kernel(
    const unsigned short* __restrict__ Wb, const unsigned short* __restrict__ Ot,
    const float* __restrict__ bo, const float* __restrict__ gamma,
    const float* __restrict__ xin, float* __restrict__ out) {
    __shared__ unsigned short As[128 * 64];
    __shared__ unsigned short Bs[128 * 64];
    int n = blockIdx.z;
    const unsigned short* A = Wb + (size_t)3 * 262144;
    const unsigned short* B = Ot + (size_t)n * S_DIM * C_DIM;
    int tid = threadIdx.x;
    int wid = tid >> 6, lane = tid & 63;
    int wm = wid >> 1, wn = wid & 1;
    int lr = lane & 15, lq = lane >> 4;
    int bm = blockIdx.y * 128, bt = blockIdx.x * 128;
    int r_in = lane >> 3, c8 = (lane & 7) * 8;

    f32x4 zero = {0.f, 0.f, 0.f, 0.f};
    f32x4 acc[4][4];
#pragma unroll
    for (int i = 0; i < 4; ++i)
#pragma unroll
        for (int j = 0; j < 4; ++j) acc[i][j] = zero;

    for (int ks = 0; ks < 8; ++ks) {
#pragma unroll
        for (int q = 0; q < 4; ++q) {
            int row = wid * 32 + q * 8;
            gload_lds16(A + (size_t)(bm + row + r_in) * C_DIM + ks * 64 + c8, &As[row * 64]);
            gload_lds16(B + (size_t)(bt + row + r_in) * C_DIM + ks * 64 + c8, &Bs[row * 64]);
        }
        __syncthreads();
#pragma unroll
        for (int kk = 0; kk < 2; ++kk) {
            s16x8 af[4], bf[4];
#pragma unroll
            for (int i = 0; i < 4; ++i)
                af[i] = *(const s16x8*)&As[(wm * 64 + i * 16 + lr) * 64 + kk * 32 + lq * 8];
#pragma unroll
            for (int j = 0; j < 4; ++j)
                bf[j] = *(const s16x8*)&Bs[(wn * 64 + j * 16 + lr) * 64 + kk * 32 + lq * 8];
#pragma unroll
            for (int i = 0; i < 4; ++i)
#pragma unroll
                for (int j = 0; j < 4; ++j)
                    acc[i][j] = __builtin_amdgcn_mfma_f32_16x16x32_bf16(af[i], bf[j], acc[i][j], 0, 0, 0);
        }
        __syncthreads();
    }

    float g = gamma[0];
#pragma unroll
    for (int i = 0; i < 4; ++i) {
        int obase = bm + wm * 64 + i * 16 + lq * 4;
#pragma unroll
        for (int j = 0; j < 4; ++j) {
            int t = bt + wn * 64 + j * 16 + lr;
#pragma unroll
            for (int r = 0; r < 4; ++r) {
                int o = obase + r;
                size_t idx = ((size_t)(n * C_DIM + o)) * S_DIM + t;
                out[idx] = g * (acc[i][j][r] + bo[o]) + xin[idx];
            }
        }
    }
}

extern "C" void kernel_launch(void* const* d_in, const int* in_sizes, int n_in,
                              void* d_out, int out_size, void* d_ws, size_t ws_size,
                              hipStream_t stream) {
    const float* x  = (const float*)d_in[0];
    const float* Wq = (const float*)d_in[1];
    const float* bq = (const float*)d_in[2];
    const float* Wk = (const float*)d_in[3];
    const float* bk = (const float*)d_in[4];
    const float* Wv = (const float*)d_in[5];
    const float* bv = (const float*)d_in[6];
    const float* Wo = (const float*)d_in[7];
    const float* bo = (const float*)d_in[8];
    const float* gamma = (const float*)d_in[9];
    float* out = (float*)d_out;

    char* ws = (char*)d_ws;
    unsigned short* Wb = (unsigned short*)ws;                         // 2 MB
    unsigned short* Xt = (unsigned short*)(ws + ((size_t)2  << 20));  // 8 MB
    unsigned short* Qt = (unsigned short*)(ws + ((size_t)10 << 20));  // 8 MB
    unsigned short* Kt = (unsigned short*)(ws + ((size_t)18 << 20));  // 8 MB
    unsigned short* Vb = (unsigned short*)(ws + ((size_t)26 << 20));  // 8 MB
    unsigned short* Ot = (unsigned short*)(ws + ((size_t)34 << 20));  // 8 MB (ends 42 MB)

    wconv_kernel<<<dim3(1024, 4), 256, 0, stream>>>(Wq, Wk, Wv, Wo, Wb);
    xpose_kernel<<<dim3(32, 16, 2), 256, 0, stream>>>(x, Xt);
    qkv_gemm_kernel<<<dim3(32, 4, 6), 256, 0, stream>>>(Wb, Xt, bq, bk, bv, Qt, Kt, Vb);
    attn_kernel<<<512, 256, 0, stream>>>(Qt, Kt, Vb, Ot);
    out_gemm_kernel<<<dim3(32, 4, 2), 256, 0, stream>>>(Wb, Ot, bo, gamma, x, out);
}

// Round 14
// 150.365 us; speedup vs baseline: 1.0519x; 1.0519x over previous
//
#include <hip/hip_runtime.h>
#include <hip/hip_bf16.h>
#include <hip/hip_fp8.h>

typedef __attribute__((ext_vector_type(4))) float f32x4;
typedef __attribute__((ext_vector_type(16))) float f32x16;
typedef __attribute__((ext_vector_type(8))) short s16x8;
typedef __attribute__((ext_vector_type(4))) unsigned short us16x4;
typedef __attribute__((ext_vector_type(4))) unsigned int u32x4;

#define C_DIM 512
#define S_DIM 4096
#define NB 2
#define NH 8
#define HD 64

// Q prescale: 1/sqrt(64) * log2(e), so attention logits are in exp2 domain
#define QSCALE 0.1803368801111244f

__device__ __forceinline__ unsigned short f2bf(float f) {
    union { float f; unsigned u; } v; v.f = f;
    unsigned r = v.u + 0x7FFFu + ((v.u >> 16) & 1u);
    return (unsigned short)(r >> 16);
}

__device__ __forceinline__ unsigned char f2fp8(float f) {
    __hip_fp8_e4m3 t(f);
    return *reinterpret_cast<unsigned char*>(&t);
}

__device__ __forceinline__ float dev_exp2(float x) {
    float r;
    asm("v_exp_f32 %0, %1" : "=v"(r) : "v"(x));
    return r;
}

__device__ __forceinline__ unsigned cvt_pk_bf16(float lo, float hi) {
    unsigned r;
    asm("v_cvt_pk_bf16_f32 %0, %1, %2" : "=v"(r) : "v"(lo), "v"(hi));
    return r;
}

// v_permlane32_swap_b32 a, b : a[0:31] <-> b[32:63]
__device__ __forceinline__ void lane_swap(unsigned& a, unsigned& b) {
    asm("v_permlane32_swap_b32 %0, %1" : "+v"(a), "+v"(b));
}

// async global -> LDS, 16B per lane; dest = base + lane*16 (base wave-uniform)
__device__ __forceinline__ void gload_lds16(const void* g, void* l) {
    __builtin_amdgcn_global_load_lds(
        (const __attribute__((address_space(1))) void*)g,
        (__attribute__((address_space(3))) void*)l, 16, 0, 0);
}

// ---------------- K0a: weights fp32 -> bf16 ----------------
__global__ __launch_bounds__(256) void wconv_kernel(
    const float* __restrict__ Wq, const float* __restrict__ Wk,
    const float* __restrict__ Wv, const float* __restrict__ Wo,
    unsigned short* __restrict__ Wb) {
    int i = blockIdx.x * 256 + threadIdx.x;          // 0..262143
    int y = blockIdx.y;                               // 0..3
    const float* src = (y == 0) ? Wq : (y == 1) ? Wk : (y == 2) ? Wv : Wo;
    Wb[(size_t)y * 262144 + i] = f2bf(src[i]);
}

// ---------------- K0b: x [N][C][S] f32 -> Xt [N][S][C] bf16 (vectorized, R10-proven) ----
__global__ __launch_bounds__(256) void xpose_kernel(
    const float* __restrict__ x, unsigned short* __restrict__ Xt) {
    __shared__ float tile[32][132];
    int n = blockIdx.z;
    int s0 = blockIdx.x * 128;
    int c0 = blockIdx.y * 32;
    int t = threadIdx.x;
    int cr = t >> 3, scol = (t & 7) * 16;
    const float* src = &x[((size_t)n * C_DIM + c0 + cr) * S_DIM + s0 + scol];
#pragma unroll
    for (int i = 0; i < 4; ++i)
        *(f32x4*)&tile[cr][scol + i * 4] = *(const f32x4*)&src[i * 4];
    __syncthreads();
    int sr = t >> 1, ch = (t & 1) * 16;
    unsigned short* dst = &Xt[((size_t)n * S_DIM + s0 + sr) * C_DIM + c0 + ch];
#pragma unroll
    for (int half = 0; half < 2; ++half) {
        s16x8 pk;
#pragma unroll
        for (int j = 0; j < 8; ++j)
            pk[j] = (short)f2bf(tile[ch + half * 8 + j][sr]);
        *(s16x8*)&dst[half * 8] = pk;
    }
}

// ---------------- K1: QKV projection GEMM (global_load_lds staging) ----------------
// w=0 -> Q8 fp8 e4m3 [nh][S][64] (prescaled by QSCALE); w=1 -> K8 fp8 e4m3 same layout;
// w=2 -> Vb bf16 [N][C][S] channel-major.
__global__ __launch_bounds__(256) void qkv_gemm_kernel(
    const unsigned short* __restrict__ Wb, const unsigned short* __restrict__ Xt,
    const float* __restrict__ bq, const float* __restrict__ bk, const float* __restrict__ bv,
    unsigned char* __restrict__ Q8, unsigned char* __restrict__ K8,
    unsigned short* __restrict__ Vb) {
    __shared__ unsigned short As[128 * 64];
    __shared__ unsigned short Bs[128 * 64];
    int w = blockIdx.z >> 1;
    int n = blockIdx.z & 1;
    const unsigned short* A = Wb + (size_t)w * 262144;
    const unsigned short* B = Xt + (size_t)n * S_DIM * C_DIM;
    int tid = threadIdx.x;
    int wid = tid >> 6, lane = tid & 63;
    int wm = wid >> 1, wn = wid & 1;
    int lr = lane & 15, lq = lane >> 4;
    int bm = blockIdx.y * 128, bt = blockIdx.x * 128;
    int r_in = lane >> 3, c8 = (lane & 7) * 8;   // staging: 8 rows x 64 cols per issue

    f32x4 zero = {0.f, 0.f, 0.f, 0.f};
    f32x4 acc[4][4];
#pragma unroll
    for (int i = 0; i < 4; ++i)
#pragma unroll
        for (int j = 0; j < 4; ++j) acc[i][j] = zero;

    for (int ks = 0; ks < 8; ++ks) {
#pragma unroll
        for (int q = 0; q < 4; ++q) {
            int row = wid * 32 + q * 8;
            gload_lds16(A + (size_t)(bm + row + r_in) * C_DIM + ks * 64 + c8, &As[row * 64]);
            gload_lds16(B + (size_t)(bt + row + r_in) * C_DIM + ks * 64 + c8, &Bs[row * 64]);
        }
        __syncthreads();
#pragma unroll
        for (int kk = 0; kk < 2; ++kk) {
            s16x8 af[4], bf[4];
#pragma unroll
            for (int i = 0; i < 4; ++i)
                af[i] = *(const s16x8*)&As[(wm * 64 + i * 16 + lr) * 64 + kk * 32 + lq * 8];
#pragma unroll
            for (int j = 0; j < 4; ++j)
                bf[j] = *(const s16x8*)&Bs[(wn * 64 + j * 16 + lr) * 64 + kk * 32 + lq * 8];
#pragma unroll
            for (int i = 0; i < 4; ++i)
#pragma unroll
                for (int j = 0; j < 4; ++j)
                    acc[i][j] = __builtin_amdgcn_mfma_f32_16x16x32_bf16(af[i], bf[j], acc[i][j], 0, 0, 0);
        }
        __syncthreads();
    }

    const float* bias = (w == 0) ? bq : (w == 1) ? bk : bv;
#pragma unroll
    for (int i = 0; i < 4; ++i) {
        int obase = bm + wm * 64 + i * 16 + lq * 4;
#pragma unroll
        for (int j = 0; j < 4; ++j) {
            int t = bt + wn * 64 + j * 16 + lr;
            if (w == 0) {
                unsigned char pk[4];
#pragma unroll
                for (int r = 0; r < 4; ++r)
                    pk[r] = f2fp8((acc[i][j][r] + bias[obase + r]) * QSCALE);
                int h = obase >> 6, d = obase & 63;
                *(unsigned int*)&Q8[(((size_t)(n * NH + h) * S_DIM) + t) * HD + d] =
                    *(unsigned int*)pk;
            } else if (w == 1) {
                unsigned char pk[4];
#pragma unroll
                for (int r = 0; r < 4; ++r) pk[r] = f2fp8(acc[i][j][r] + bias[obase + r]);
                int h = obase >> 6, d = obase & 63;
                *(unsigned int*)&K8[(((size_t)(n * NH + h) * S_DIM) + t) * HD + d] =
                    *(unsigned int*)pk;
            } else {
#pragma unroll
                for (int r = 0; r < 4; ++r) {
                    int o = obase + r;
                    Vb[((size_t)(n * C_DIM + o)) * S_DIM + t] = f2bf(acc[i][j][r] + bias[o]);
                }
            }
        }
    }
}

// ---------------- K2: flash attention (R11 structure; fp8 QK^T path) ----------------
// Mq=32/wave, NO split, no-max softmax, l-sum via ones-MFMA on matrix pipe.
// Q8,K8 fp8 e4m3 [nh][4096][64] (Q prescaled, exp2 domain); Vb bf16 [N][512][4096].
// QK^T via mfma_f32_32x32x16_fp8_fp8 (same shape/k-indexing/C-D layout as bf16).
// K LDS tile is 4KB of 8B slots (ds_read_b64); V path byte-identical to R11 (bf16).
// Swizzle (both tiles): phys_slot = slot ^ (row&7) ^ ((row>>3)&3)  (verified 0 conflicts).
__global__ __launch_bounds__(256) void attn_kernel(
    const unsigned char* __restrict__ Q8, const unsigned char* __restrict__ K8,
    const unsigned short* __restrict__ Vb, unsigned short* __restrict__ Ot) {
    __shared__ long Ks8[64 * 8];             // [kv][8B slot], fp8, swizzled
    __shared__ unsigned short Vs[64 * 64];   // [d][kv], bf16, swizzled 16B slots
    int tid = threadIdx.x, wid = tid >> 6, lane = tid & 63;
    int l31 = lane & 31, hi = lane >> 5;
    int radj = (l31 & 7) ^ ((l31 >> 3) & 3);

    // XCD-bijective swizzle: 512 blocks -> 64 consecutive per XCD = 2 heads
    int bidl = blockIdx.x;
    int swz = (bidl & 7) * 64 + (bidl >> 3);
    int nh = swz >> 5;          // 0..15
    int qb = swz & 31;          // 0..31
    int n = nh >> 3, h = nh & 7;
    int qrow0 = qb * 128 + wid * 32;

    const unsigned char* Qh = Q8 + (size_t)nh * S_DIM * HD;
    const unsigned char* Kh = K8 + (size_t)nh * S_DIM * HD;
    const unsigned short* Vh = Vb + ((size_t)(n * C_DIM + h * HD)) * S_DIM;

    // Q fragments (B-operand, fp8): n=lane&31 -> q, k-dim d = st*16 + hi*8 + j
    long qf8[4];
#pragma unroll
    for (int st = 0; st < 4; ++st)
        qf8[st] = *(const long*)&Qh[((size_t)(qrow0 + l31)) * HD + st * 16 + hi * 8];

    // all-ones bf16 A-frag for the l-sum MFMA
    s16x8 ones;
#pragma unroll
    for (int r = 0; r < 8; ++r) ones[r] = (short)0x3F80;

    f32x16 Oacc[2], Lacc;
#pragma unroll
    for (int jm = 0; jm < 2; ++jm)
#pragma unroll
        for (int r = 0; r < 16; ++r) Oacc[jm][r] = 0.f;
#pragma unroll
    for (int r = 0; r < 16; ++r) Lacc[r] = 0.f;

    // V staging (bf16, 8KB): rows srow0, srow0+32; swizzled 16B slot
    int srow0 = tid >> 3, sslot = tid & 7;
    int wslot = (sslot ^ (srow0 & 7) ^ ((srow0 >> 3) & 3)) * 8;
    // K staging (fp8, 4KB): 1 x 16B per thread -> row krow, two 8B slots
    int krow = tid >> 2, ksl = (tid & 3) * 2;
    int kadj = (krow & 7) ^ ((krow >> 3) & 3);
    int kp0 = ksl ^ kadj, kp1 = (ksl + 1) ^ kadj;

    u32x4 kreg;
    s16x8 vreg[2];
    kreg = *(const u32x4*)&Kh[((size_t)krow) * HD + ksl * 8];
#pragma unroll
    for (int q = 0; q < 2; ++q) {
        int row = srow0 + q * 32;
        vreg[q] = *(const s16x8*)&Vh[((size_t)row) * S_DIM + sslot * 8];
    }

    for (int kt = 0; kt < 64; ++kt) {
        Ks8[krow * 8 + kp0] = ((const long*)&kreg)[0];
        Ks8[krow * 8 + kp1] = ((const long*)&kreg)[1];
#pragma unroll
        for (int q = 0; q < 2; ++q) {
            int row = srow0 + q * 32;
            *(s16x8*)&Vs[row * 64 + wslot] = vreg[q];
        }
        __syncthreads();
        if (kt < 63) {   // prefetch next tile into regs; overlaps compute below
            kreg = *(const u32x4*)&Kh[((size_t)((kt + 1) * 64 + krow)) * HD + ksl * 8];
#pragma unroll
            for (int q = 0; q < 2; ++q) {
                int row = srow0 + q * 32;
                vreg[q] = *(const s16x8*)&Vh[((size_t)row) * S_DIM + (kt + 1) * 64 + sslot * 8];
            }
        }

        // ---- QK^T (fp8): D[kv][q] per jm tile; A=K rows, B=Q ----
        f32x16 s_[2];
#pragma unroll
        for (int jm = 0; jm < 2; ++jm) {
#pragma unroll
            for (int r = 0; r < 16; ++r) s_[jm][r] = 0.f;
            int arow = jm * 32 + l31;
#pragma unroll
            for (int st = 0; st < 4; ++st) {
                long kf = Ks8[arow * 8 + ((2 * st + hi) ^ radj)];
                s_[jm] = __builtin_amdgcn_mfma_f32_32x32x16_fp8_fp8(kf, qf8[st], s_[jm], 0, 0, 0);
            }
        }

        // ---- p = exp2(s) directly (no max pass), pack to PV B-frags in-register ----
        s16x8 pf[2][2];
#pragma unroll
        for (int jm = 0; jm < 2; ++jm) {
            unsigned pk0 = cvt_pk_bf16(dev_exp2(s_[jm][0]),  dev_exp2(s_[jm][1]));
            unsigned pk1 = cvt_pk_bf16(dev_exp2(s_[jm][2]),  dev_exp2(s_[jm][3]));
            unsigned pk2 = cvt_pk_bf16(dev_exp2(s_[jm][4]),  dev_exp2(s_[jm][5]));
            unsigned pk3 = cvt_pk_bf16(dev_exp2(s_[jm][6]),  dev_exp2(s_[jm][7]));
            unsigned pk4 = cvt_pk_bf16(dev_exp2(s_[jm][8]),  dev_exp2(s_[jm][9]));
            unsigned pk5 = cvt_pk_bf16(dev_exp2(s_[jm][10]), dev_exp2(s_[jm][11]));
            unsigned pk6 = cvt_pk_bf16(dev_exp2(s_[jm][12]), dev_exp2(s_[jm][13]));
            unsigned pk7 = cvt_pk_bf16(dev_exp2(s_[jm][14]), dev_exp2(s_[jm][15]));
            lane_swap(pk2, pk0);   // pk2 -> w2, pk0 -> w0 of step 0
            lane_swap(pk3, pk1);   // pk3 -> w3, pk1 -> w1
            lane_swap(pk6, pk4);   // step 1
            lane_swap(pk7, pk5);
            u32x4 w0 = {pk0, pk1, pk2, pk3};
            u32x4 w1 = {pk4, pk5, pk6, pk7};
            pf[jm][0] = __builtin_bit_cast(s16x8, w0);
            pf[jm][1] = __builtin_bit_cast(s16x8, w1);
        }

        // ---- l-sum on the matrix pipe: Lacc[*][q] += sum_kv P[kv][q] ----
#pragma unroll
        for (int jm = 0; jm < 2; ++jm)
#pragma unroll
            for (int st = 0; st < 2; ++st)
                Lacc = __builtin_amdgcn_mfma_f32_32x32x16_bf16(ones, pf[jm][st], Lacc, 0, 0, 0);

        // ---- PV: Oacc[d-tile jm2] += V^T[d][kv] x P[q][kv] ----
#pragma unroll
        for (int jm2 = 0; jm2 < 2; ++jm2) {
            int vrow = jm2 * 32 + l31;
#pragma unroll
            for (int jm = 0; jm < 2; ++jm)
#pragma unroll
                for (int st = 0; st < 2; ++st) {
                    s16x8 vf = *(const s16x8*)&Vs[vrow * 64 + ((jm * 4 + st * 2 + hi) ^ radj) * 8];
                    Oacc[jm2] = __builtin_amdgcn_mfma_f32_32x32x16_bf16(vf, pf[jm][st], Oacc[jm2], 0, 0, 0);
                }
        }
        __syncthreads();
    }

    float inv = 1.f / Lacc[0];
    int token = qrow0 + l31;
    unsigned short* orow = Ot + ((size_t)n * S_DIM + token) * C_DIM + h * HD;
#pragma unroll
    for (int jm2 = 0; jm2 < 2; ++jm2)
#pragma unroll
        for (int rq = 0; rq < 4; ++rq) {
            int d = jm2 * 32 + 8 * rq + 4 * hi;
            us16x4 pk;
#pragma unroll
            for (int r = 0; r < 4; ++r) pk[r] = f2bf(Oacc[jm2][rq * 4 + r] * inv);
            *(us16x4*)&orow[d] = pk;
        }
}

// ---------------- K3: output projection + residual (global_load_lds staging) ----------------
__global__ __launch_bounds__(256) void out_gemm_kernel(
    const unsigned short* __restrict__ Wb, const unsigned short* __restrict__ Ot,
    const float* __restrict__ bo, const float* __restrict__ gamma,
    const float* __restrict__ xin, float* __restrict__ out) {
    __shared__ unsigned short As[128 * 64];
    __shared__ unsigned short Bs[128 * 64];
    int n = blockIdx.z;
    const unsigned short* A = Wb + (size_t)3 * 262144;
    const unsigned short* B = Ot + (size_t)n * S_DIM * C_DIM;
    int tid = threadIdx.x;
    int wid = tid >> 6, lane = tid & 63;
    int wm = wid >> 1, wn = wid & 1;
    int lr = lane & 15, lq = lane >> 4;
    int bm = blockIdx.y * 128, bt = blockIdx.x * 128;
    int r_in = lane >> 3, c8 = (lane & 7) * 8;

    f32x4 zero = {0.f, 0.f, 0.f, 0.f};
    f32x4 acc[4][4];
#pragma unroll
    for (int i = 0; i < 4; ++i)
#pragma unroll
        for (int j = 0; j < 4; ++j) acc[i][j] = zero;

    for (int ks = 0; ks < 8; ++ks) {
#pragma unroll
        for (int q = 0; q < 4; ++q) {
            int row = wid * 32 + q * 8;
            gload_lds16(A + (size_t)(bm + row + r_in) * C_DIM + ks * 64 + c8, &As[row * 64]);
            gload_lds16(B + (size_t)(bt + row + r_in) * C_DIM + ks * 64 + c8, &Bs[row * 64]);
        }
        __syncthreads();
#pragma unroll
        for (int kk = 0; kk < 2; ++kk) {
            s16x8 af[4], bf[4];
#pragma unroll
            for (int i = 0; i < 4; ++i)
                af[i] = *(const s16x8*)&As[(wm * 64 + i * 16 + lr) * 64 + kk * 32 + lq * 8];
#pragma unroll
            for (int j = 0; j < 4; ++j)
                bf[j] = *(const s16x8*)&Bs[(wn * 64 + j * 16 + lr) * 64 + kk * 32 + lq * 8];
#pragma unroll
            for (int i = 0; i < 4; ++i)
#pragma unroll
                for (int j = 0; j < 4; ++j)
                    acc[i][j] = __builtin_amdgcn_mfma_f32_16x16x32_bf16(af[i], bf[j], acc[i][j], 0, 0, 0);
        }
        __syncthreads();
    }

    float g = gamma[0];
#pragma unroll
    for (int i = 0; i < 4; ++i) {
        int obase = bm + wm * 64 + i * 16 + lq * 4;
#pragma unroll
        for (int j = 0; j < 4; ++j) {
            int t = bt + wn * 64 + j * 16 + lr;
#pragma unroll
            for (int r = 0; r < 4; ++r) {
                int o = obase + r;
                size_t idx = ((size_t)(n * C_DIM + o)) * S_DIM + t;
                out[idx] = g * (acc[i][j][r] + bo[o]) + xin[idx];
            }
        }
    }
}

extern "C" void kernel_launch(void* const* d_in, const int* in_sizes, int n_in,
                              void* d_out, int out_size, void* d_ws, size_t ws_size,
                              hipStream_t stream) {
    const float* x  = (const float*)d_in[0];
    const float* Wq = (const float*)d_in[1];
    const float* bq = (const float*)d_in[2];
    const float* Wk = (const float*)d_in[3];
    const float* bk = (const float*)d_in[4];
    const float* Wv = (const float*)d_in[5];
    const float* bv = (const float*)d_in[6];
    const float* Wo = (const float*)d_in[7];
    const float* bo = (const float*)d_in[8];
    const float* gamma = (const float*)d_in[9];
    float* out = (float*)d_out;

    char* ws = (char*)d_ws;
    unsigned short* Wb = (unsigned short*)ws;                         // 2 MB
    unsigned short* Xt = (unsigned short*)(ws + ((size_t)2  << 20));  // 8 MB
    unsigned char*  Q8 = (unsigned char*)(ws + ((size_t)10 << 20));   // 4 MB fp8
    unsigned char*  K8 = (unsigned char*)(ws + ((size_t)14 << 20));   // 4 MB fp8
    unsigned short* Vb = (unsigned short*)(ws + ((size_t)18 << 20));  // 8 MB
    unsigned short* Ot = (unsigned short*)(ws + ((size_t)26 << 20));  // 8 MB (ends 34 MB)

    wconv_kernel<<<dim3(1024, 4), 256, 0, stream>>>(Wq, Wk, Wv, Wo, Wb);
    xpose_kernel<<<dim3(32, 16, 2), 256, 0, stream>>>(x, Xt);
    qkv_gemm_kernel<<<dim3(32, 4, 6), 256, 0, stream>>>(Wb, Xt, bq, bk, bv, Q8, K8, Vb);
    attn_kernel<<<512, 256, 0, stream>>>(Q8, K8, Vb, Ot);
    out_gemm_kernel<<<dim3(32, 4, 2), 256, 0, stream>>>(Wb, Ot, bo, gamma, x, out);
}

// Round 15
// 146.893 us; speedup vs baseline: 1.0767x; 1.0236x over previous
//
#include <hip/hip_runtime.h>
#include <hip/hip_bf16.h>

typedef __attribute__((ext_vector_type(4))) float f32x4;
typedef __attribute__((ext_vector_type(16))) float f32x16;
typedef __attribute__((ext_vector_type(8))) short s16x8;
typedef __attribute__((ext_vector_type(4))) unsigned short us16x4;
typedef __attribute__((ext_vector_type(4))) unsigned int u32x4;

#define C_DIM 512
#define S_DIM 4096
#define NB 2
#define NH 8
#define HD 64

// Q prescale: 1/sqrt(64) * log2(e), so attention logits are in exp2 domain
#define QSCALE 0.1803368801111244f

__device__ __forceinline__ unsigned short f2bf(float f) {
    union { float f; unsigned u; } v; v.f = f;
    unsigned r = v.u + 0x7FFFu + ((v.u >> 16) & 1u);
    return (unsigned short)(r >> 16);
}

__device__ __forceinline__ float dev_exp2(float x) {
    float r;
    asm("v_exp_f32 %0, %1" : "=v"(r) : "v"(x));
    return r;
}

__device__ __forceinline__ unsigned cvt_pk_bf16(float lo, float hi) {
    unsigned r;
    asm("v_cvt_pk_bf16_f32 %0, %1, %2" : "=v"(r) : "v"(lo), "v"(hi));
    return r;
}

// v_permlane32_swap_b32 a, b : a[0:31] <-> b[32:63]
__device__ __forceinline__ void lane_swap(unsigned& a, unsigned& b) {
    asm("v_permlane32_swap_b32 %0, %1" : "+v"(a), "+v"(b));
}

// async global -> LDS, 16B per lane; dest = base + lane*16
__device__ __forceinline__ void gload_lds16(const void* g, void* l) {
    __builtin_amdgcn_global_load_lds(
        (const __attribute__((address_space(1))) void*)g,
        (__attribute__((address_space(3))) void*)l, 16, 0, 0);
}

// ---------------- K0a: weights fp32 -> bf16 ----------------
__global__ __launch_bounds__(256) void wconv_kernel(
    const float* __restrict__ Wq, const float* __restrict__ Wk,
    const float* __restrict__ Wv, const float* __restrict__ Wo,
    unsigned short* __restrict__ Wb) {
    int i = blockIdx.x * 256 + threadIdx.x;          // 0..262143
    int y = blockIdx.y;                               // 0..3
    const float* src = (y == 0) ? Wq : (y == 1) ? Wk : (y == 2) ? Wv : Wo;
    Wb[(size_t)y * 262144 + i] = f2bf(src[i]);
}

// ---------------- K0b: x [N][C][S] f32 -> Xt [N][S][C] bf16 (vectorized, R10-proven) ----
// Block: 32 channels x 128 spatial. float4 global loads (16B/lane), padded f32 LDS
// tile (132 stride -> max 2-way bank alias = free), s16x8 16B global stores.
__global__ __launch_bounds__(256) void xpose_kernel(
    const float* __restrict__ x, unsigned short* __restrict__ Xt) {
    __shared__ float tile[32][132];
    int n = blockIdx.z;
    int s0 = blockIdx.x * 128;
    int c0 = blockIdx.y * 32;
    int t = threadIdx.x;
    int cr = t >> 3, scol = (t & 7) * 16;
    const float* src = &x[((size_t)n * C_DIM + c0 + cr) * S_DIM + s0 + scol];
#pragma unroll
    for (int i = 0; i < 4; ++i)
        *(f32x4*)&tile[cr][scol + i * 4] = *(const f32x4*)&src[i * 4];
    __syncthreads();
    int sr = t >> 1, ch = (t & 1) * 16;
    unsigned short* dst = &Xt[((size_t)n * S_DIM + s0 + sr) * C_DIM + c0 + ch];
#pragma unroll
    for (int half = 0; half < 2; ++half) {
        s16x8 pk;
#pragma unroll
        for (int j = 0; j < 8; ++j)
            pk[j] = (short)f2bf(tile[ch + half * 8 + j][sr]);
        *(s16x8*)&dst[half * 8] = pk;
    }
}

// ---------------- K1: QKV projection GEMM (global_load_lds staging) ----------------
__global__ __launch_bounds__(256) void qkv_gemm_kernel(
    const unsigned short* __restrict__ Wb, const unsigned short* __restrict__ Xt,
    const float* __restrict__ bq, const float* __restrict__ bk, const float* __restrict__ bv,
    unsigned short* __restrict__ Qt, unsigned short* __restrict__ Kt,
    unsigned short* __restrict__ Vb) {
    __shared__ unsigned short As[128 * 64];
    __shared__ unsigned short Bs[128 * 64];
    int w = blockIdx.z >> 1;
    int n = blockIdx.z & 1;
    const unsigned short* A = Wb + (size_t)w * 262144;
    const unsigned short* B = Xt + (size_t)n * S_DIM * C_DIM;
    int tid = threadIdx.x;
    int wid = tid >> 6, lane = tid & 63;
    int wm = wid >> 1, wn = wid & 1;
    int lr = lane & 15, lq = lane >> 4;
    int bm = blockIdx.y * 128, bt = blockIdx.x * 128;
    int r_in = lane >> 3, c8 = (lane & 7) * 8;   // staging: 8 rows x 64 cols per issue

    f32x4 zero = {0.f, 0.f, 0.f, 0.f};
    f32x4 acc[4][4];
#pragma unroll
    for (int i = 0; i < 4; ++i)
#pragma unroll
        for (int j = 0; j < 4; ++j) acc[i][j] = zero;

    for (int ks = 0; ks < 8; ++ks) {
#pragma unroll
        for (int q = 0; q < 4; ++q) {
            int row = wid * 32 + q * 8;
            gload_lds16(A + (size_t)(bm + row + r_in) * C_DIM + ks * 64 + c8, &As[row * 64]);
            gload_lds16(B + (size_t)(bt + row + r_in) * C_DIM + ks * 64 + c8, &Bs[row * 64]);
        }
        __syncthreads();
#pragma unroll
        for (int kk = 0; kk < 2; ++kk) {
            s16x8 af[4], bf[4];
#pragma unroll
            for (int i = 0; i < 4; ++i)
                af[i] = *(const s16x8*)&As[(wm * 64 + i * 16 + lr) * 64 + kk * 32 + lq * 8];
#pragma unroll
            for (int j = 0; j < 4; ++j)
                bf[j] = *(const s16x8*)&Bs[(wn * 64 + j * 16 + lr) * 64 + kk * 32 + lq * 8];
#pragma unroll
            for (int i = 0; i < 4; ++i)
#pragma unroll
                for (int j = 0; j < 4; ++j)
                    acc[i][j] = __builtin_amdgcn_mfma_f32_16x16x32_bf16(af[i], bf[j], acc[i][j], 0, 0, 0);
        }
        __syncthreads();
    }

    const float* bias = (w == 0) ? bq : (w == 1) ? bk : bv;
#pragma unroll
    for (int i = 0; i < 4; ++i) {
        int obase = bm + wm * 64 + i * 16 + lq * 4;
#pragma unroll
        for (int j = 0; j < 4; ++j) {
            int t = bt + wn * 64 + j * 16 + lr;
            if (w == 0) {
                us16x4 pk;
#pragma unroll
                for (int r = 0; r < 4; ++r)
                    pk[r] = f2bf((acc[i][j][r] + bias[obase + r]) * QSCALE);
                int h = obase >> 6, d = obase & 63;
                *(us16x4*)&Qt[(((size_t)(n * NH + h) * S_DIM) + t) * HD + d] = pk;
            } else if (w == 1) {
                us16x4 pk;
#pragma unroll
                for (int r = 0; r < 4; ++r) pk[r] = f2bf(acc[i][j][r] + bias[obase + r]);
                int h = obase >> 6, d = obase & 63;
                *(us16x4*)&Kt[(((size_t)(n * NH + h) * S_DIM) + t) * HD + d] = pk;
            } else {
#pragma unroll
                for (int r = 0; r < 4; ++r) {
                    int o = obase + r;
                    Vb[((size_t)(n * C_DIM + o)) * S_DIM + t] = f2bf(acc[i][j][r] + bias[o]);
                }
            }
        }
    }
}

// ---------------- K2: flash attention (R9 exact: session-best 85.0us) ----------------
// Mq=32/wave, NO split, no-max softmax, l-sum via ones-MFMA on matrix pipe.
// Qt,Kt [nh][4096][64] token-major bf16 (Q prescaled, exp2 domain); Vb [N][512][4096]
// Ot [N][4096][512] token-major bf16 (written directly, normalized).
// Block: 256 threads = 4 waves x 32 q-rows; 64 KV tiles; single-buffer LDS.
// Swizzle: phys_slot = slot ^ (row&7) ^ ((row>>3)&3)  (verified 0 conflicts).
__global__ __launch_bounds__(256) void attn_kernel(
    const unsigned short* __restrict__ Qt, const unsigned short* __restrict__ Kt,
    const unsigned short* __restrict__ Vb, unsigned short* __restrict__ Ot) {
    __shared__ unsigned short Ks[64 * 64];   // [kv][d]
    __shared__ unsigned short Vs[64 * 64];   // [d][kv]
    int tid = threadIdx.x, wid = tid >> 6, lane = tid & 63;
    int l31 = lane & 31, hi = lane >> 5;
    int radj = (l31 & 7) ^ ((l31 >> 3) & 3);

    // XCD-bijective swizzle: 512 blocks -> 64 consecutive per XCD = 2 heads
    int bidl = blockIdx.x;
    int swz = (bidl & 7) * 64 + (bidl >> 3);
    int nh = swz >> 5;          // 0..15
    int qb = swz & 31;          // 0..31
    int n = nh >> 3, h = nh & 7;
    int qrow0 = qb * 128 + wid * 32;

    const unsigned short* Qh = Qt + (size_t)nh * S_DIM * HD;
    const unsigned short* Kh = Kt + (size_t)nh * S_DIM * HD;
    const unsigned short* Vh = Vb + ((size_t)(n * C_DIM + h * HD)) * S_DIM;

    // Q fragments (B-operand): n=lane&31 -> q, k-dim d = st*16 + hi*8 + j
    s16x8 qf[4];
#pragma unroll
    for (int st = 0; st < 4; ++st)
        qf[st] = *(const s16x8*)&Qh[((size_t)(qrow0 + l31)) * HD + st * 16 + hi * 8];

    // all-ones bf16 A-frag for the l-sum MFMA
    s16x8 ones;
#pragma unroll
    for (int r = 0; r < 8; ++r) ones[r] = (short)0x3F80;

    f32x16 Oacc[2], Lacc;
#pragma unroll
    for (int jm = 0; jm < 2; ++jm)
#pragma unroll
        for (int r = 0; r < 16; ++r) Oacc[jm][r] = 0.f;
#pragma unroll
    for (int r = 0; r < 16; ++r) Lacc[r] = 0.f;

    // staging: rows srow0, srow0+32; swizzled slot (invariant under row+32)
    int srow0 = tid >> 3, sslot = tid & 7;
    int wslot = (sslot ^ (srow0 & 7) ^ ((srow0 >> 3) & 3)) * 8;

    s16x8 kreg[2], vreg[2];
#pragma unroll
    for (int q = 0; q < 2; ++q) {
        int row = srow0 + q * 32;
        kreg[q] = *(const s16x8*)&Kh[((size_t)row) * HD + sslot * 8];
        vreg[q] = *(const s16x8*)&Vh[((size_t)row) * S_DIM + sslot * 8];
    }

    for (int kt = 0; kt < 64; ++kt) {
#pragma unroll
        for (int q = 0; q < 2; ++q) {
            int row = srow0 + q * 32;
            *(s16x8*)&Ks[row * 64 + wslot] = kreg[q];
            *(s16x8*)&Vs[row * 64 + wslot] = vreg[q];
        }
        __syncthreads();
        if (kt < 63) {   // prefetch next tile into regs; overlaps compute below
#pragma unroll
            for (int q = 0; q < 2; ++q) {
                int row = srow0 + q * 32;
                kreg[q] = *(const s16x8*)&Kh[((size_t)((kt + 1) * 64 + row)) * HD + sslot * 8];
                vreg[q] = *(const s16x8*)&Vh[((size_t)row) * S_DIM + (kt + 1) * 64 + sslot * 8];
            }
        }

        // ---- QK^T: D[kv][q] per jm tile; A=K rows, B=Q ----
        f32x16 s_[2];
#pragma unroll
        for (int jm = 0; jm < 2; ++jm) {
#pragma unroll
            for (int r = 0; r < 16; ++r) s_[jm][r] = 0.f;
            int arow = jm * 32 + l31;
#pragma unroll
            for (int st = 0; st < 4; ++st) {
                s16x8 kf = *(const s16x8*)&Ks[arow * 64 + ((2 * st + hi) ^ radj) * 8];
                s_[jm] = __builtin_amdgcn_mfma_f32_32x32x16_bf16(kf, qf[st], s_[jm], 0, 0, 0);
            }
        }

        // ---- p = exp2(s) directly (no max pass), pack to PV B-frags in-register ----
        s16x8 pf[2][2];
#pragma unroll
        for (int jm = 0; jm < 2; ++jm) {
            unsigned pk0 = cvt_pk_bf16(dev_exp2(s_[jm][0]),  dev_exp2(s_[jm][1]));
            unsigned pk1 = cvt_pk_bf16(dev_exp2(s_[jm][2]),  dev_exp2(s_[jm][3]));
            unsigned pk2 = cvt_pk_bf16(dev_exp2(s_[jm][4]),  dev_exp2(s_[jm][5]));
            unsigned pk3 = cvt_pk_bf16(dev_exp2(s_[jm][6]),  dev_exp2(s_[jm][7]));
            unsigned pk4 = cvt_pk_bf16(dev_exp2(s_[jm][8]),  dev_exp2(s_[jm][9]));
            unsigned pk5 = cvt_pk_bf16(dev_exp2(s_[jm][10]), dev_exp2(s_[jm][11]));
            unsigned pk6 = cvt_pk_bf16(dev_exp2(s_[jm][12]), dev_exp2(s_[jm][13]));
            unsigned pk7 = cvt_pk_bf16(dev_exp2(s_[jm][14]), dev_exp2(s_[jm][15]));
            lane_swap(pk2, pk0);   // pk2 -> w2, pk0 -> w0 of step 0
            lane_swap(pk3, pk1);   // pk3 -> w3, pk1 -> w1
            lane_swap(pk6, pk4);   // step 1
            lane_swap(pk7, pk5);
            u32x4 w0 = {pk0, pk1, pk2, pk3};
            u32x4 w1 = {pk4, pk5, pk6, pk7};
            pf[jm][0] = __builtin_bit_cast(s16x8, w0);
            pf[jm][1] = __builtin_bit_cast(s16x8, w1);
        }

        // ---- l-sum on the matrix pipe: Lacc[*][q] += sum_kv P[kv][q] ----
#pragma unroll
        for (int jm = 0; jm < 2; ++jm)
#pragma unroll
            for (int st = 0; st < 2; ++st)
                Lacc = __builtin_amdgcn_mfma_f32_32x32x16_bf16(ones, pf[jm][st], Lacc, 0, 0, 0);

        // ---- PV: Oacc[d-tile jm2] += V^T[d][kv] x P[q][kv] ----
#pragma unroll
        for (int jm2 = 0; jm2 < 2; ++jm2) {
            int vrow = jm2 * 32 + l31;
#pragma unroll
            for (int jm = 0; jm < 2; ++jm)
#pragma unroll
                for (int st = 0; st < 2; ++st) {
                    s16x8 vf = *(const s16x8*)&Vs[vrow * 64 + ((jm * 4 + st * 2 + hi) ^ radj) * 8];
                    Oacc[jm2] = __builtin_amdgcn_mfma_f32_32x32x16_bf16(vf, pf[jm][st], Oacc[jm2], 0, 0, 0);
                }
        }
        __syncthreads();
    }

    float inv = 1.f / Lacc[0];
    int token = qrow0 + l31;
    unsigned short* orow = Ot + ((size_t)n * S_DIM + token) * C_DIM + h * HD;
#pragma unroll
    for (int jm2 = 0; jm2 < 2; ++jm2)
#pragma unroll
        for (int rq = 0; rq < 4; ++rq) {
            int d = jm2 * 32 + 8 * rq + 4 * hi;
            us16x4 pk;
#pragma unroll
            for (int r = 0; r < 4; ++r) pk[r] = f2bf(Oacc[jm2][rq * 4 + r] * inv);
            *(us16x4*)&orow[d] = pk;
        }
}

// ---------------- K3: output projection + residual (global_load_lds staging) ----------------
__global__ __launch_bounds__(256) void out_gemm_kernel(
    const unsigned short* __restrict__ Wb, const unsigned short* __restrict__ Ot,
    const float* __restrict__ bo, const float* __restrict__ gamma,
    const float* __restrict__ xin, float* __restrict__ out) {
    __shared__ unsigned short As[128 * 64];
    __shared__ unsigned short Bs[128 * 64];
    int n = blockIdx.z;
    const unsigned short* A = Wb + (size_t)3 * 262144;
    const unsigned short* B = Ot + (size_t)n * S_DIM * C_DIM;
    int tid = threadIdx.x;
    int wid = tid >> 6, lane = tid & 63;
    int wm = wid >> 1, wn = wid & 1;
    int lr = lane & 15, lq = lane >> 4;
    int bm = blockIdx.y * 128, bt = blockIdx.x * 128;
    int r_in = lane >> 3, c8 = (lane & 7) * 8;

    f32x4 zero = {0.f, 0.f, 0.f, 0.f};
    f32x4 acc[4][4];
#pragma unroll
    for (int i = 0; i < 4; ++i)
#pragma unroll
        for (int j = 0; j < 4; ++j) acc[i][j] = zero;

    for (int ks = 0; ks < 8; ++ks) {
#pragma unroll
        for (int q = 0; q < 4; ++q) {
            int row = wid * 32 + q * 8;
            gload_lds16(A + (size_t)(bm + row + r_in) * C_DIM + ks * 64 + c8, &As[row * 64]);
            gload_lds16(B + (size_t)(bt + row + r_in) * C_DIM + ks * 64 + c8, &Bs[row * 64]);
        }
        __syncthreads();
#pragma unroll
        for (int kk = 0; kk < 2; ++kk) {
            s16x8 af[4], bf[4];
#pragma unroll
            for (int i = 0; i < 4; ++i)
                af[i] = *(const s16x8*)&As[(wm * 64 + i * 16 + lr) * 64 + kk * 32 + lq * 8];
#pragma unroll
            for (int j = 0; j < 4; ++j)
                bf[j] = *(const s16x8*)&Bs[(wn * 64 + j * 16 + lr) * 64 + kk * 32 + lq * 8];
#pragma unroll
            for (int i = 0; i < 4; ++i)
#pragma unroll
                for (int j = 0; j < 4; ++j)
                    acc[i][j] = __builtin_amdgcn_mfma_f32_16x16x32_bf16(af[i], bf[j], acc[i][j], 0, 0, 0);
        }
        __syncthreads();
    }

    float g = gamma[0];
#pragma unroll
    for (int i = 0; i < 4; ++i) {
        int obase = bm + wm * 64 + i * 16 + lq * 4;
#pragma unroll
        for (int j = 0; j < 4; ++j) {
            int t = bt + wn * 64 + j * 16 + lr;
#pragma unroll
            for (int r = 0; r < 4; ++r) {
                int o = obase + r;
                size_t idx = ((size_t)(n * C_DIM + o)) * S_DIM + t;
                out[idx] = g * (acc[i][j][r] + bo[o]) + xin[idx];
            }
        }
    }
}

extern "C" void kernel_launch(void* const* d_in, const int* in_sizes, int n_in,
                              void* d_out, int out_size, void* d_ws, size_t ws_size,
                              hipStream_t stream) {
    const float* x  = (const float*)d_in[0];
    const float* Wq = (const float*)d_in[1];
    const float* bq = (const float*)d_in[2];
    const float* Wk = (const float*)d_in[3];
    const float* bk = (const float*)d_in[4];
    const float* Wv = (const float*)d_in[5];
    const float* bv = (const float*)d_in[6];
    const float* Wo = (const float*)d_in[7];
    const float* bo = (const float*)d_in[8];
    const float* gamma = (const float*)d_in[9];
    float* out = (float*)d_out;

    char* ws = (char*)d_ws;
    unsigned short* Wb = (unsigned short*)ws;                         // 2 MB
    unsigned short* Xt = (unsigned short*)(ws + ((size_t)2  << 20));  // 8 MB
    unsigned short* Qt = (unsigned short*)(ws + ((size_t)10 << 20));  // 8 MB
    unsigned short* Kt = (unsigned short*)(ws + ((size_t)18 << 20));  // 8 MB
    unsigned short* Vb = (unsigned short*)(ws + ((size_t)26 << 20));  // 8 MB
    unsigned short* Ot = (unsigned short*)(ws + ((size_t)34 << 20));  // 8 MB (ends 42 MB)

    wconv_kernel<<<dim3(1024, 4), 256, 0, stream>>>(Wq, Wk, Wv, Wo, Wb);
    xpose_kernel<<<dim3(32, 16, 2), 256, 0, stream>>>(x, Xt);
    qkv_gemm_kernel<<<dim3(32, 4, 6), 256, 0, stream>>>(Wb, Xt, bq, bk, bv, Qt, Kt, Vb);
    attn_kernel<<<512, 256, 0, stream>>>(Qt, Kt, Vb, Ot);
    out_gemm_kernel<<<dim3(32, 4, 2), 256, 0, stream>>>(Wb, Ot, bo, gamma, x, out);
}